// Round 3
// baseline (392.357 us; speedup 1.0000x reference)
//
#include <hip/hip_runtime.h>
#include <hip/hip_bf16.h>
#include <stdint.h>

typedef __bf16 bf16x8 __attribute__((ext_vector_type(8)));
typedef float f32x4 __attribute__((ext_vector_type(4)));
typedef unsigned short u16;
typedef u16 u16x8 __attribute__((ext_vector_type(8)));
typedef uint32_t u32x4 __attribute__((ext_vector_type(4)));

#define RES 512
#define C3 144
#define CPP 48
#define HID 256
#define TPB 128
#define K0 160
#define BK_PAD 264
#define PLANE_ELEMS ((size_t)RES * RES * CPP)
#define NPTS 524288
#define NBLK (NPTS / TPB)        // 4096
// fragment-major weight image (u16 offsets)
#define L0_U16 (HID * K0)        // 40960
#define L12_U16 (HID * HID)      // 65536
#define L1_IMG L0_U16
#define L2_IMG (L0_U16 + L12_U16)
#define WIMG_U16 (L0_U16 + 2 * L12_U16)

static __device__ __forceinline__ float bf2f(u16 u) {
    uint32_t x = ((uint32_t)u) << 16;
    union { uint32_t i; float f; } c; c.i = x; return c.f;
}
static __device__ __forceinline__ u16 f2bf(float f) {
    __bf16 h = (__bf16)f;
    return __builtin_bit_cast(u16, h);
}

// ---- preprocessing: (144,512,512) f32 -> 3 x [512][512][48] bf16 ----
__global__ __launch_bounds__(256) void k_transpose(const float* __restrict__ tri,
                                                   u16* __restrict__ planes) {
    int id = blockIdx.x * 256 + threadIdx.x;
    int p = id >> 18;
    int rem = id & ((1 << 18) - 1);
    int y = rem >> 9, x = rem & (RES - 1);
    const float* src = tri + ((size_t)p * CPP) * (RES * RES) + (size_t)y * RES + x;
    u16 outv[CPP] __attribute__((aligned(16)));
    #pragma unroll
    for (int c = 0; c < CPP; ++c)
        outv[c] = f2bf(src[(size_t)c * (RES * RES)]);
    u16* dst = planes + (size_t)id * CPP;
    #pragma unroll
    for (int j = 0; j < 6; ++j)
        ((u32x4*)dst)[j] = ((const u32x4*)outv)[j];
}

// ---- weights -> fragment-major bf16 image ----
// L0 frag addr = ((w*5+kb)*2+mf)*512 + lane*8 + j   (kb 0..4)
// L1/L2      = ((w*8+kb)*2+mf)*512 + lane*8 + j     (kb 0..7)
// value = W[w*32 + mf*16 + (lane&15)][kb*32 + (lane>>4)*8 + j]
__global__ __launch_bounds__(256) void k_prep_w(const float* __restrict__ w0,
                                                const float* __restrict__ w1,
                                                const float* __restrict__ w2,
                                                u16* __restrict__ wimg) {
    int id = blockIdx.x * 256 + threadIdx.x;   // 65536 threads
    if (id < L0_U16) {
        int j = id & 7;
        int f = id >> 3;
        int lane = f & 63;
        int g2 = f >> 6;          // 0..79
        int mf = g2 & 1;
        int t2 = g2 >> 1;         // 0..39
        int kb = t2 % 5;
        int w  = t2 / 5;
        int m = w * 32 + mf * 16 + (lane & 15);
        int k = kb * 32 + (lane >> 4) * 8 + j;
        wimg[id] = f2bf(k < C3 ? w0[m * C3 + k] : 0.f);
    }
    {
        int j = id & 7;
        int f = id >> 3;
        int lane = f & 63;
        int g2 = f >> 6;          // 0..127
        int mf = g2 & 1;
        int t2 = g2 >> 1;         // 0..63
        int kb = t2 & 7;
        int w  = t2 >> 3;
        int m = w * 32 + mf * 16 + (lane & 15);
        int k = kb * 32 + (lane >> 4) * 8 + j;
        wimg[L1_IMG + id] = f2bf(w1[m * HID + k]);
        wimg[L2_IMG + id] = f2bf(w2[m * HID + k]);
    }
}

// buf layout: row = point (0..127), row stride BK_PAD u16 (528 B).
// Within a row, data is stored in 16B chunks at index c16 ^ (row & 7)
// (XOR swizzle, applied identically on write and read -> bijective per row).

// A-fragments from global image (coalesced 1KB/wave-load, L2-hot);
// B-fragments from LDS buf. nf processed in halves of 4 (live-set control).
template<int NKB>
static __device__ __forceinline__ void do_kbloop(
    const u16* __restrict__ wl, const u16* buf, f32x4 (&acc)[2][8],
    int wave, int lane)
{
    const int r = lane & 15;
    const int g = lane >> 4;
    const int sx = lane & 7;             // row&7 for rows 16nf+r
    #pragma unroll
    for (int kb = 0; kb < NKB; ++kb) {
        bf16x8 a[2];
        #pragma unroll
        for (int mf = 0; mf < 2; ++mf)
            a[mf] = *(const bf16x8*)(wl + ((size_t)((wave * NKB + kb) * 2 + mf)) * 512 + lane * 8);
        const int co = ((4 * kb + g) ^ sx) << 3;   // swizzled chunk offset (u16)
        #pragma unroll
        for (int h = 0; h < 2; ++h) {
            bf16x8 b[4];
            #pragma unroll
            for (int nf = 0; nf < 4; ++nf)
                b[nf] = *(const bf16x8*)(buf + ((h * 4 + nf) * 16 + r) * BK_PAD + co);
            #pragma unroll
            for (int mf = 0; mf < 2; ++mf)
                #pragma unroll
                for (int nf = 0; nf < 4; ++nf)
                    acc[mf][h * 4 + nf] = __builtin_amdgcn_mfma_f32_16x16x32_bf16(
                        a[mf], b[nf], acc[mf][h * 4 + nf], 0, 0, 0);
        }
    }
}

static __device__ __forceinline__ void epilogue(
    f32x4 (&acc)[2][8], const float* __restrict__ bias,
    u16* buf, int wave, int lane)
{
    const int r = lane & 15;
    const int g = lane >> 4;
    const int sx = lane & 7;
    #pragma unroll
    for (int mf = 0; mf < 2; ++mf) {
        int mb = wave * 32 + mf * 16 + g * 4;
        // swizzled in-row u16 offset of this 8B activation chunk
        int wo = ((((mb >> 3)) ^ sx) << 3) + (g & 1) * 4;
        f32x4 bb = *(const f32x4*)(bias + mb);
        #pragma unroll
        for (int nf = 0; nf < 8; ++nf) {
            int n = nf * 16 + r;
            union { u16 u[4]; unsigned long long v; } pk;
            #pragma unroll
            for (int q = 0; q < 4; ++q) {
                float v = acc[mf][nf][q] + bb[q];
                pk.u[q] = f2bf(v > 0.0f ? v : 0.0f);
            }
            *(unsigned long long*)(buf + n * BK_PAD + wo) = pk.v;
        }
    }
}

// 128-point fused kernel: 512 threads (8 waves, pure m-split), 2 blocks/CU.
__global__ __launch_bounds__(512)
__attribute__((amdgpu_waves_per_eu(4, 4)))
void k_fused(
    const float* __restrict__ points,
    const u16* __restrict__ planes,
    const u16* __restrict__ wimg,
    const float* __restrict__ b0, const float* __restrict__ b1,
    const float* __restrict__ b2,
    const float* __restrict__ wa, const float* __restrict__ ba,
    float* __restrict__ outp)
{
    __shared__ u16 buf[TPB * BK_PAD];          // 67584 B
    __shared__ uint32_t soffs[3][4][TPB];      // 6144 B
    __shared__ float    swts[3][4][TPB];       // 6144 B (reused as alpha partials)
    const int t = threadIdx.x;
    const int lane = t & 63;
    const int wave = t >> 6;
    const int r = lane & 15;
    const int g = lane >> 4;
    const int p0 = blockIdx.x * TPB;

    // zero K-pad chunks c16 = 18,19 (cols [144,160)), swizzled per row
    if (t < TPB) {
        u32x4 z = {0, 0, 0, 0};
        int s = t & 7;
        *(u32x4*)&buf[t * BK_PAD + ((18 ^ s) << 3)] = z;
        *(u32x4*)&buf[t * BK_PAD + ((19 ^ s) << 3)] = z;
    }

    // ---- coords: one task per (plane, point) = 384 tasks ----
    if (t < 3 * TPB) {
        const int pln = t >> 7;
        const int pt  = t & (TPB - 1);
        const float* pp = points + (size_t)(p0 + pt) * 3;
        float px = pp[0] * 2.f - 1.f;
        float py = pp[1] * 2.f - 1.f;
        float pz = pp[2] * 2.f - 1.f;
        float gx, gy;
        if (pln == 0)      { gx = px; gy = py; }   // plane_xy
        else if (pln == 1) { gx = py; gy = pz; }   // plane_yz
        else               { gx = px; gy = pz; }   // plane_xz
        float ix = (gx + 1.f) * 0.5f * (float)(RES - 1);
        float iy = (gy + 1.f) * 0.5f * (float)(RES - 1);
        float fx = floorf(ix), fy = floorf(iy);
        float wx1 = ix - fx, wy1 = iy - fy;
        int x0 = ::min(::max((int)fx, 0), RES - 1);
        int x1 = ::min(::max((int)fx + 1, 0), RES - 1);
        int y0 = ::min(::max((int)fy, 0), RES - 1);
        int y1 = ::min(::max((int)fy + 1, 0), RES - 1);
        soffs[pln][0][pt] = (uint32_t)(y0 * RES + x0) * (CPP * 2);
        soffs[pln][1][pt] = (uint32_t)(y0 * RES + x1) * (CPP * 2);
        soffs[pln][2][pt] = (uint32_t)(y1 * RES + x0) * (CPP * 2);
        soffs[pln][3][pt] = (uint32_t)(y1 * RES + x1) * (CPP * 2);
        swts[pln][0][pt] = (1.f - wy1) * (1.f - wx1);
        swts[pln][1][pt] = (1.f - wy1) * wx1;
        swts[pln][2][pt] = wy1 * (1.f - wx1);
        swts[pln][3][pt] = wy1 * wx1;
    }
    __syncthreads();

    // ---- gather: 128 pts x 3 planes x 6 chunks = 2304 tasks, 6 lanes/corner ----
    #pragma unroll
    for (int rr = 0; rr < 5; ++rr) {
        int task = rr * 512 + t;
        if (task < TPB * 18) {
            int pt = task / 18;
            int rem = task - pt * 18;
            int pi = rem / 6;
            int ch = rem - pi * 6;
            const char* pl = (const char*)planes + (size_t)pi * (PLANE_ELEMS * 2);
            uint32_t co = (uint32_t)ch * 16;
            u16x8 v0 = *(const u16x8*)(pl + soffs[pi][0][pt] + co);
            u16x8 v1 = *(const u16x8*)(pl + soffs[pi][1][pt] + co);
            u16x8 v2 = *(const u16x8*)(pl + soffs[pi][2][pt] + co);
            u16x8 v3 = *(const u16x8*)(pl + soffs[pi][3][pt] + co);
            float W0 = swts[pi][0][pt];
            float W1 = swts[pi][1][pt];
            float W2 = swts[pi][2][pt];
            float W3 = swts[pi][3][pt];
            u16x8 res;
            #pragma unroll
            for (int j = 0; j < 8; ++j) {
                float v = W0 * bf2f(v0[j]) + W1 * bf2f(v1[j])
                        + W2 * bf2f(v2[j]) + W3 * bf2f(v3[j]);
                res[j] = f2bf(v);
            }
            // chunk c16 = 6*pi+ch, swizzled by row (pt&7)
            *(u16x8*)&buf[pt * BK_PAD + (((6 * pi + ch) ^ (pt & 7)) << 3)] = res;
        }
    }
    __syncthreads();

    // ---- layers 0 and 1 (activations round-trip through LDS, in place) ----
    {
        f32x4 acc[2][8] = {{}};
        do_kbloop<5>(wimg, buf, acc, wave, lane);
        __syncthreads();
        epilogue(acc, b0, buf, wave, lane);
        __syncthreads();
    }
    {
        f32x4 acc[2][8] = {{}};
        do_kbloop<8>(wimg + L1_IMG, buf, acc, wave, lane);
        __syncthreads();
        epilogue(acc, b1, buf, wave, lane);
        __syncthreads();
    }

    // ---- layer 2 + fused alpha: output never touches LDS ----
    {
        f32x4 acc[2][8] = {{}};
        do_kbloop<8>(wimg + L2_IMG, buf, acc, wave, lane);
        // alpha partial per thread: sum over its 8 m-rows (mf x q), per point
        float pa[8];
        #pragma unroll
        for (int nf = 0; nf < 8; ++nf) pa[nf] = 0.f;
        #pragma unroll
        for (int mf = 0; mf < 2; ++mf) {
            int mb = wave * 32 + mf * 16 + g * 4;
            f32x4 bb = *(const f32x4*)(b2 + mb);
            f32x4 wv = *(const f32x4*)(wa + mb);
            #pragma unroll
            for (int nf = 0; nf < 8; ++nf) {
                #pragma unroll
                for (int q = 0; q < 4; ++q) {
                    float v = acc[mf][nf][q] + bb[q];
                    pa[nf] += wv[q] * (v > 0.f ? v : 0.f);
                }
            }
        }
        // reduce over g-groups (lanes r, r+16, r+32, r+48)
        #pragma unroll
        for (int nf = 0; nf < 8; ++nf) {
            pa[nf] += __shfl_xor(pa[nf], 16, 64);
            pa[nf] += __shfl_xor(pa[nf], 32, 64);
        }
        // per-wave partials into LDS (overlay dead swts: 8*128 floats = 4KB)
        float* part = &swts[0][0][0];
        if (g == 0) {
            #pragma unroll
            for (int nf = 0; nf < 8; ++nf)
                part[wave * TPB + nf * 16 + r] = pa[nf];
        }
        __syncthreads();
        if (t < TPB) {
            float s = ba[0];
            #pragma unroll
            for (int w = 0; w < 8; ++w) s += part[w * TPB + t];
            outp[p0 + t] = s;
        }
    }
}

extern "C" void kernel_launch(void* const* d_in, const int* in_sizes, int n_in,
                              void* d_out, int out_size, void* d_ws, size_t ws_size,
                              hipStream_t stream) {
    const float* points = (const float*)d_in[0];
    const float* tri    = (const float*)d_in[1];
    const float* w0 = (const float*)d_in[2];
    const float* b0 = (const float*)d_in[3];
    const float* w1 = (const float*)d_in[4];
    const float* b1 = (const float*)d_in[5];
    const float* w2 = (const float*)d_in[6];
    const float* b2 = (const float*)d_in[7];
    const float* wa = (const float*)d_in[8];
    const float* ba = (const float*)d_in[9];
    float* outp = (float*)d_out;

    char* wsb = (char*)d_ws;
    u16* planes = (u16*)wsb;                          // 75,497,472 B
    size_t off = 3 * PLANE_ELEMS * 2;
    u16* wimg = (u16*)(wsb + off);                    // 344,064 B

    k_transpose<<<(3 * RES * RES) / 256, 256, 0, stream>>>(tri, planes);
    k_prep_w<<<256, 256, 0, stream>>>(w0, w1, w2, wimg);
    k_fused<<<NBLK, 512, 0, stream>>>(points, planes, wimg,
                                      b0, b1, b2, wa, ba, outp);
}

// Round 4
// 295.676 us; speedup vs baseline: 1.3270x; 1.3270x over previous
//
#include <hip/hip_runtime.h>
#include <hip/hip_bf16.h>
#include <stdint.h>

typedef __bf16 bf16x8 __attribute__((ext_vector_type(8)));
typedef float f32x4 __attribute__((ext_vector_type(4)));
typedef unsigned short u16;
typedef u16 u16x8 __attribute__((ext_vector_type(8)));
typedef uint32_t u32x4 __attribute__((ext_vector_type(4)));

#define RES 512
#define C3 144
#define CPP 48
#define HID 256
#define TPB 256                  // points per block
#define NTHR 1024                // 16 waves: 8 m-waves x 2 n-halves
#define K0 160
#define BK_PAD 264
#define PLANE_ELEMS ((size_t)RES * RES * CPP)
#define NPTS 524288
#define NBLK (NPTS / TPB)        // 2048
// fragment-major weight image (u16 offsets)
#define L0_U16 (HID * K0)        // 40960
#define L12_U16 (HID * HID)      // 65536
#define L1_IMG L0_U16
#define L2_IMG (L0_U16 + L12_U16)
#define WIMG_U16 (L0_U16 + 2 * L12_U16)

static __device__ __forceinline__ float bf2f(u16 u) {
    uint32_t x = ((uint32_t)u) << 16;
    union { uint32_t i; float f; } c; c.i = x; return c.f;
}
static __device__ __forceinline__ u16 f2bf(float f) {
    __bf16 h = (__bf16)f;
    return __builtin_bit_cast(u16, h);
}

// ---- preprocessing: (144,512,512) f32 -> 3 x [512][512][48] bf16 ----
__global__ __launch_bounds__(256) void k_transpose(const float* __restrict__ tri,
                                                   u16* __restrict__ planes) {
    int id = blockIdx.x * 256 + threadIdx.x;
    int p = id >> 18;
    int rem = id & ((1 << 18) - 1);
    int y = rem >> 9, x = rem & (RES - 1);
    const float* src = tri + ((size_t)p * CPP) * (RES * RES) + (size_t)y * RES + x;
    u16 outv[CPP] __attribute__((aligned(16)));
    #pragma unroll
    for (int c = 0; c < CPP; ++c)
        outv[c] = f2bf(src[(size_t)c * (RES * RES)]);
    u16* dst = planes + (size_t)id * CPP;
    #pragma unroll
    for (int j = 0; j < 6; ++j)
        ((u32x4*)dst)[j] = ((const u32x4*)outv)[j];
}

// ---- weights -> fragment-major bf16 image (identical to R0) ----
// L0 frag addr = ((w*5+kb)*2+mf)*512 + lane*8 + j   (kb 0..4)
// L1/L2      = ((w*8+kb)*2+mf)*512 + lane*8 + j     (kb 0..7)
// value = W[w*32 + mf*16 + (lane&15)][kb*32 + (lane>>4)*8 + j]
__global__ __launch_bounds__(256) void k_prep_w(const float* __restrict__ w0,
                                                const float* __restrict__ w1,
                                                const float* __restrict__ w2,
                                                u16* __restrict__ wimg) {
    int id = blockIdx.x * 256 + threadIdx.x;   // 65536 threads
    if (id < L0_U16) {
        int j = id & 7;
        int f = id >> 3;
        int lane = f & 63;
        int g2 = f >> 6;          // 0..79
        int mf = g2 & 1;
        int t2 = g2 >> 1;         // 0..39
        int kb = t2 % 5;
        int w  = t2 / 5;
        int m = w * 32 + mf * 16 + (lane & 15);
        int k = kb * 32 + (lane >> 4) * 8 + j;
        wimg[id] = f2bf(k < C3 ? w0[m * C3 + k] : 0.f);
    }
    {
        int j = id & 7;
        int f = id >> 3;
        int lane = f & 63;
        int g2 = f >> 6;          // 0..127
        int mf = g2 & 1;
        int t2 = g2 >> 1;         // 0..63
        int kb = t2 & 7;
        int w  = t2 >> 3;
        int m = w * 32 + mf * 16 + (lane & 15);
        int k = kb * 32 + (lane >> 4) * 8 + j;
        wimg[L1_IMG + id] = f2bf(w1[m * HID + k]);
        wimg[L2_IMG + id] = f2bf(w2[m * HID + k]);
    }
}

// Wave (mw, nh): 32 m-rows [32mw,32mw+32) x 128 points [128nh,128nh+128).
// Per-lane addressing identical to R0 (linear chunks, no swizzle); the only
// delta is the nh*128 row offset on B-reads / epilogue writes.
template<int NKB>
static __device__ __forceinline__ void do_kbloop(
    const u16* __restrict__ wl, const u16* buf, f32x4 (&acc)[2][8],
    int mw, int nh, int lane)
{
    const int r = lane & 15;
    const int g = lane >> 4;
    const int rb = nh * 128;
    #pragma unroll
    for (int kb = 0; kb < NKB; ++kb) {
        bf16x8 a[2];
        #pragma unroll
        for (int mf = 0; mf < 2; ++mf)
            a[mf] = *(const bf16x8*)(wl + ((size_t)((mw * NKB + kb) * 2 + mf)) * 512 + lane * 8);
        #pragma unroll
        for (int h = 0; h < 2; ++h) {
            bf16x8 b[4];
            #pragma unroll
            for (int nf = 0; nf < 4; ++nf)
                b[nf] = *(const bf16x8*)(buf + (rb + (h * 4 + nf) * 16 + r) * BK_PAD + kb * 32 + g * 8);
            #pragma unroll
            for (int mf = 0; mf < 2; ++mf)
                #pragma unroll
                for (int nf = 0; nf < 4; ++nf)
                    acc[mf][h * 4 + nf] = __builtin_amdgcn_mfma_f32_16x16x32_bf16(
                        a[mf], b[nf], acc[mf][h * 4 + nf], 0, 0, 0);
        }
    }
}

static __device__ __forceinline__ void epilogue(
    f32x4 (&acc)[2][8], const float* __restrict__ bias,
    u16* buf, int mw, int nh, int lane)
{
    const int r = lane & 15;
    const int g = lane >> 4;
    const int rb = nh * 128;
    #pragma unroll
    for (int mf = 0; mf < 2; ++mf) {
        int mb = mw * 32 + mf * 16 + g * 4;
        f32x4 bb = *(const f32x4*)(bias + mb);
        #pragma unroll
        for (int nf = 0; nf < 8; ++nf) {
            int n = rb + nf * 16 + r;
            union { u16 u[4]; unsigned long long v; } pk;
            #pragma unroll
            for (int q = 0; q < 4; ++q) {
                float v = acc[mf][nf][q] + bb[q];
                pk.u[q] = f2bf(v > 0.0f ? v : 0.0f);
            }
            *(unsigned long long*)(buf + n * BK_PAD + mb) = pk.v;
        }
    }
}

// 256-point fused kernel: 1024 threads (16 waves = 8 mw x 2 nh), 1 block/CU
// (16 waves/CU = 4/SIMD, same residency as the 2x8-wave R0 config).
__global__ __launch_bounds__(1024)
__attribute__((amdgpu_waves_per_eu(4, 4)))
void k_fused(
    const float* __restrict__ points,
    const u16* __restrict__ planes,
    const u16* __restrict__ wimg,
    const float* __restrict__ b0, const float* __restrict__ b1,
    const float* __restrict__ b2,
    const float* __restrict__ wa, const float* __restrict__ ba,
    float* __restrict__ outp)
{
    __shared__ u16 buf[TPB * BK_PAD];          // 135168 B
    __shared__ uint32_t soffs[3][4][TPB];      // 12288 B
    __shared__ float    swts[3][4][TPB];       // 12288 B (reused as alpha partials)
    const int t = threadIdx.x;
    const int lane = t & 63;
    const int wave = t >> 6;                   // 0..15
    const int mw = wave >> 1;                  // 0..7
    const int nh = wave & 1;                   // 0..1
    const int r = lane & 15;
    const int g = lane >> 4;
    const int p0 = blockIdx.x * TPB;

    // zero K-pad cols [144,160)
    if (t < TPB) {
        u32x4 z = {0, 0, 0, 0};
        *(u32x4*)&buf[t * BK_PAD + 144] = z;
        *(u32x4*)&buf[t * BK_PAD + 152] = z;
    }

    // ---- coords: one task per (plane, point) = 768 tasks ----
    if (t < 3 * TPB) {
        const int pln = t >> 8;
        const int pt  = t & (TPB - 1);
        const float* pp = points + (size_t)(p0 + pt) * 3;
        float px = pp[0] * 2.f - 1.f;
        float py = pp[1] * 2.f - 1.f;
        float pz = pp[2] * 2.f - 1.f;
        float gx, gy;
        if (pln == 0)      { gx = px; gy = py; }   // plane_xy
        else if (pln == 1) { gx = py; gy = pz; }   // plane_yz
        else               { gx = px; gy = pz; }   // plane_xz
        float ix = (gx + 1.f) * 0.5f * (float)(RES - 1);
        float iy = (gy + 1.f) * 0.5f * (float)(RES - 1);
        float fx = floorf(ix), fy = floorf(iy);
        float wx1 = ix - fx, wy1 = iy - fy;
        int x0 = ::min(::max((int)fx, 0), RES - 1);
        int x1 = ::min(::max((int)fx + 1, 0), RES - 1);
        int y0 = ::min(::max((int)fy, 0), RES - 1);
        int y1 = ::min(::max((int)fy + 1, 0), RES - 1);
        soffs[pln][0][pt] = (uint32_t)(y0 * RES + x0) * (CPP * 2);
        soffs[pln][1][pt] = (uint32_t)(y0 * RES + x1) * (CPP * 2);
        soffs[pln][2][pt] = (uint32_t)(y1 * RES + x0) * (CPP * 2);
        soffs[pln][3][pt] = (uint32_t)(y1 * RES + x1) * (CPP * 2);
        swts[pln][0][pt] = (1.f - wy1) * (1.f - wx1);
        swts[pln][1][pt] = (1.f - wy1) * wx1;
        swts[pln][2][pt] = wy1 * (1.f - wx1);
        swts[pln][3][pt] = wy1 * wx1;
    }
    __syncthreads();                               // S1

    // ---- gather: 256 pts x 3 planes x 6 chunks = 4608 tasks ----
    #pragma unroll
    for (int rr = 0; rr < 5; ++rr) {
        int task = rr * NTHR + t;
        if (task < TPB * 18) {
            int pt = task / 18;
            int rem = task - pt * 18;
            int pi = rem / 6;
            int ch = rem - pi * 6;
            const char* pl = (const char*)planes + (size_t)pi * (PLANE_ELEMS * 2);
            uint32_t co = (uint32_t)ch * 16;
            u16x8 v0 = *(const u16x8*)(pl + soffs[pi][0][pt] + co);
            u16x8 v1 = *(const u16x8*)(pl + soffs[pi][1][pt] + co);
            u16x8 v2 = *(const u16x8*)(pl + soffs[pi][2][pt] + co);
            u16x8 v3 = *(const u16x8*)(pl + soffs[pi][3][pt] + co);
            float W0 = swts[pi][0][pt];
            float W1 = swts[pi][1][pt];
            float W2 = swts[pi][2][pt];
            float W3 = swts[pi][3][pt];
            u16x8 res;
            #pragma unroll
            for (int j = 0; j < 8; ++j) {
                float v = W0 * bf2f(v0[j]) + W1 * bf2f(v1[j])
                        + W2 * bf2f(v2[j]) + W3 * bf2f(v3[j]);
                res[j] = f2bf(v);
            }
            *(u16x8*)&buf[pt * BK_PAD + pi * CPP + ch * 8] = res;
        }
    }
    __syncthreads();                               // S2

    // ---- layers 0 and 1 (activations round-trip through LDS, in place) ----
    {
        f32x4 acc[2][8] = {{}};
        do_kbloop<5>(wimg, buf, acc, mw, nh, lane);
        __syncthreads();                           // S3
        epilogue(acc, b0, buf, mw, nh, lane);
        __syncthreads();                           // S4
    }
    {
        f32x4 acc[2][8] = {{}};
        do_kbloop<8>(wimg + L1_IMG, buf, acc, mw, nh, lane);
        __syncthreads();                           // S5
        epilogue(acc, b1, buf, mw, nh, lane);
        __syncthreads();                           // S6
    }

    // ---- layer 2 + fused alpha: output never touches LDS ----
    {
        f32x4 acc[2][8] = {{}};
        do_kbloop<8>(wimg + L2_IMG, buf, acc, mw, nh, lane);
        // alpha partial per thread: sum over its 8 m-rows (mf x q), per point
        float pa[8];
        #pragma unroll
        for (int nf = 0; nf < 8; ++nf) pa[nf] = 0.f;
        #pragma unroll
        for (int mf = 0; mf < 2; ++mf) {
            int mb = mw * 32 + mf * 16 + g * 4;
            f32x4 bb = *(const f32x4*)(b2 + mb);
            f32x4 wv = *(const f32x4*)(wa + mb);
            #pragma unroll
            for (int nf = 0; nf < 8; ++nf) {
                #pragma unroll
                for (int q = 0; q < 4; ++q) {
                    float v = acc[mf][nf][q] + bb[q];
                    pa[nf] += wv[q] * (v > 0.f ? v : 0.f);
                }
            }
        }
        // reduce over g-groups (lanes r, r+16, r+32, r+48)
        #pragma unroll
        for (int nf = 0; nf < 8; ++nf) {
            pa[nf] += __shfl_xor(pa[nf], 16, 64);
            pa[nf] += __shfl_xor(pa[nf], 32, 64);
        }
        // per-wave partials into LDS (overlay dead swts: 16*128 floats = 8KB)
        float* part = &swts[0][0][0];
        if (g == 0) {
            #pragma unroll
            for (int nf = 0; nf < 8; ++nf)
                part[wave * 128 + nf * 16 + r] = pa[nf];
        }
        __syncthreads();                           // S7
        if (t < TPB) {
            const int nhp = t >> 7;
            const int lp  = t & 127;
            float s = ba[0];
            #pragma unroll
            for (int w = 0; w < 8; ++w) s += part[(w * 2 + nhp) * 128 + lp];
            outp[p0 + t] = s;
        }
    }
}

extern "C" void kernel_launch(void* const* d_in, const int* in_sizes, int n_in,
                              void* d_out, int out_size, void* d_ws, size_t ws_size,
                              hipStream_t stream) {
    const float* points = (const float*)d_in[0];
    const float* tri    = (const float*)d_in[1];
    const float* w0 = (const float*)d_in[2];
    const float* b0 = (const float*)d_in[3];
    const float* w1 = (const float*)d_in[4];
    const float* b1 = (const float*)d_in[5];
    const float* w2 = (const float*)d_in[6];
    const float* b2 = (const float*)d_in[7];
    const float* wa = (const float*)d_in[8];
    const float* ba = (const float*)d_in[9];
    float* outp = (float*)d_out;

    char* wsb = (char*)d_ws;
    u16* planes = (u16*)wsb;                          // 75,497,472 B
    size_t off = 3 * PLANE_ELEMS * 2;
    u16* wimg = (u16*)(wsb + off);                    // 344,064 B

    k_transpose<<<(3 * RES * RES) / 256, 256, 0, stream>>>(tri, planes);
    k_prep_w<<<256, 256, 0, stream>>>(w0, w1, w2, wimg);
    k_fused<<<NBLK, NTHR, 0, stream>>>(points, planes, wimg,
                                       b0, b1, b2, wa, ba, outp);
}